// Round 1
// baseline (204.349 us; speedup 1.0000x reference)
//
#include <hip/hip_runtime.h>

#define HW 1659      // 21*79
#define PADID 4096
#define EMB 20
#define HID 32
#define MAXLEN 64
#define PROJ_BLOCKS 64

typedef float v2f __attribute__((ext_vector_type(2)));

// DPP lane-permute helper (pure VALU, no LDS pipe). CTRL is an immediate.
template <int CTRL>
__device__ __forceinline__ float dppf(float v) {
    return __builtin_bit_cast(float,
        __builtin_amdgcn_update_dpp(0, __builtin_bit_cast(int, v),
                                    CTRL, 0xF, 0xF, true));
}
#define DPP_XOR1 0xB1   // quad_perm [1,0,3,2]
#define DPP_XOR2 0x4E   // quad_perm [2,3,0,1]
#define DPP_XOR7 0x141  // row_half_mirror (xor 7 within 16)
#define DPP_XORF 0x140  // row_mirror      (xor 15 within 16)

// ---------------- Kernel 1: WAVE-per-sample bag+emb, fused proj tail ----------
// Old version: 256-thread block per sample, 2 __syncthreads around the LDS
// scatter -> latency/barrier-bound (VALU 22%, HBM 28%, occ 58%). Now each
// wave owns one sample (no barriers, wave-sync via lgkmcnt), grid = B/4
// blocks = exactly 8 blocks/CU = 32 waves/CU. Compaction early-exits: with
// ~1365 expected distinct ids, ids 0..1023 almost always contain >=64, so
// rounds 1..3 of the bitmap readback are skipped.
// Blocks >= nbag compute proj[g][j] = emb_table[g] . W_ih[j] (replaces the
// separate proj_kernel launch; must only finish before rnn_kernel does).
__global__ __launch_bounds__(256, 8) void bag_emb_wave_kernel(
    const int* __restrict__ chars, const int* __restrict__ colors,
    const float* __restrict__ emb_table, const float* __restrict__ W_ih,
    float* __restrict__ out_emb, float* __restrict__ out_bag,
    float* __restrict__ proj, int nbag, int Btot)
{
    if ((int)blockIdx.x >= nbag) {
        // ---- proj tail blocks ----
        const int gid = ((int)blockIdx.x - nbag) * 256 + threadIdx.x;
        const int NP = (PADID + 1) * HID;          // 131104
        for (int idx = gid; idx < NP; idx += PROJ_BLOCKS * 256) {
            const int g = idx >> 5, j = idx & 31;
            const float* er = emb_table + (size_t)g * EMB;
            const float* wr = W_ih + j * EMB;
            float s = 0.f;
#pragma unroll
            for (int k = 0; k < EMB; k++) s += wr[k] * er[k];
            proj[idx] = s;
        }
        return;
    }

    __shared__ __align__(16) unsigned char pres[4][4096];
    __shared__ int bagl[4][64];

    const int tid  = threadIdx.x;
    const int wv   = tid >> 6;
    const int lane = tid & 63;
    const int b    = (int)blockIdx.x * 4 + wv;
    if (b >= Btot) return;

    // zero this wave's presence map (lane-contiguous b128 stores, conflict-free)
    uint4* pz = (uint4*)pres[wv];
#pragma unroll
    for (int r = 0; r < 4; r++) pz[lane + (r << 6)] = make_uint4(0u, 0u, 0u, 0u);
    bagl[wv][lane] = PADID;

    const int base = b * HW;
    const int pe = (4 - (base & 3)) & 3;          // peel to 16B alignment
    const int nv = (HW - pe) >> 2;                // always 414 int4 groups
    const int nt = HW - pe - (nv << 2);           // tail 0..3
    const int4* c4 = (const int4*)(chars + base + pe);
    const int4* k4 = (const int4*)(colors + base + pe);

    int gp = -1, gt = -1;
    if (lane < pe) gp = (chars[base + lane] << 4) + colors[base + lane];
    if (lane < nt) {
        const int i = base + pe + (nv << 2) + lane;
        gt = (chars[i] << 4) + colors[i];
    }

    // scatter presence bytes (same-wave ordering; no barrier needed)
    unsigned char* pw = pres[wv];
#pragma unroll
    for (int k = 0; k < 7; k++) {
        const int i = lane + (k << 6);
        if (i < nv) {
            const int4 c = c4[i], kk = k4[i];
            pw[(c.x << 4) + kk.x] = 1;
            pw[(c.y << 4) + kk.y] = 1;
            pw[(c.z << 4) + kk.z] = 1;
            pw[(c.w << 4) + kk.w] = 1;
        }
    }
    if (gp >= 0) pw[gp] = 1;
    if (gt >= 0) pw[gt] = 1;

    asm volatile("s_waitcnt lgkmcnt(0)" ::: "memory");

    // readback in 4 rounds of 1024 ids; round r, lane L owns ids
    // [1024r + 16L, 1024r + 16L + 16) -> (r, lane, k) lex order == id order.
    const unsigned M = 0x01010101u;
    int base_cnt = 0;
#pragma unroll 1
    for (int r = 0; r < 4; r++) {
        const uint4 w = ((const uint4*)pres[wv])[lane + (r << 6)];
        const int cnt = __popc(w.x & M) + __popc(w.y & M)
                      + __popc(w.z & M) + __popc(w.w & M);
        int pre = cnt;
#pragma unroll
        for (int d = 1; d < 64; d <<= 1) {
            const int v = __shfl_up(pre, d, 64);
            if (lane >= d) pre += v;
        }
        int p = base_cnt + pre - cnt;             // exclusive prefix in id order
        if (p < 64 && cnt) {
            const unsigned wd[4] = {w.x, w.y, w.z, w.w};
            const int idbase = (r << 10) + (lane << 4);
#pragma unroll
            for (int c = 0; c < 4; c++) {
                unsigned m = wd[c] & M;
                while (m) {
                    const int bit = __ffs((int)m) - 1;   // 0,8,16,24
                    if (p < 64) bagl[wv][p] = idbase + (c << 2) + (bit >> 3);
                    p++;
                    m &= m - 1;
                }
            }
        }
        base_cnt += __shfl(pre, 63, 64);          // wave total, uniform
        if (base_cnt >= 64) break;                // bag full -> skip later rounds
    }

    asm volatile("s_waitcnt lgkmcnt(0)" ::: "memory");

    out_bag[(size_t)b * 64 + lane] = (float)bagl[wv][lane];

    // gather embedding rows: 320 float4 over 64 lanes, coalesced writes
    const float4* tab4 = (const float4*)emb_table;
    float4* dst4 = (float4*)(out_emb + (size_t)b * (MAXLEN * EMB));
#pragma unroll
    for (int m5 = 0; m5 < 5; m5++) {
        const int q = lane + (m5 << 6);
        const int t = q / 5;
        const int mm = q - t * 5;
        const int row = bagl[wv][t];
        dst4[q] = tab4[row * 5 + mm];
    }
}

// ------ Kernel 2: packed RNN, DPP all-gather, CHUNKED pv preload (16-deep) -----
__global__ __launch_bounds__(128)
__attribute__((amdgpu_waves_per_eu(2, 2)))
void rnn_kernel(
    const float* __restrict__ proj, const float* __restrict__ bagf,
    const float* __restrict__ W_hh,
    const float* __restrict__ b_ih, const float* __restrict__ b_hh,
    float* __restrict__ out_h)
{
    const int tid  = threadIdx.x;
    const int wv   = tid >> 6;
    const int lane = tid & 63;
    const int sl   = lane >> 4;        // sample slot within wave 0..3
    const int ib   = wv * 4 + sl;      // sample slot within block 0..7
    const int jj   = lane & 15;        // owns hidden units 2jj, 2jj+1
    const int b    = blockIdx.x * 8 + ib;

    // gather-position -> pair-xor map (butterfly: xor1, xor2, xor7, xor15)
    const int GMAP[16] = {0,1,2,3, 7,6,5,4, 15,14,13,12,11,10,9,8};

    // weights: w0[m]/w1[m] = rows (2jj, 2jj+1), column pair c = jj ^ GMAP[m]
    v2f w0[16], w1[16];
    const float2* wr0 = (const float2*)(W_hh + (2 * jj) * HID);
    const float2* wr1 = (const float2*)(W_hh + (2 * jj + 1) * HID);
#pragma unroll
    for (int m = 0; m < 16; m++) {
        const int c = jj ^ GMAP[m];
        float2 a = wr0[c], bb = wr1[c];
        w0[m] = (v2f){a.x, a.y};
        w1[m] = (v2f){bb.x, bb.y};
    }
    const float sb0 = b_ih[2 * jj]     + b_hh[2 * jj];
    const float sb1 = b_ih[2 * jj + 1] + b_hh[2 * jj + 1];

    const float* bps = bagf + (size_t)b * 64;
    const float2* proj2 = (const float2*)proj;   // row g -> proj2[g*16 + jj]

    float h0 = 0.f, h1 = 0.f;

#pragma unroll
    for (int ch = 0; ch < 4; ch++) {
        // ---- preload this chunk's 16 idx + pv (independent loads, MLP) ----
        int idx[16];
#pragma unroll
        for (int i = 0; i < 16; i++) idx[i] = (int)bps[ch * 16 + i];
        float2 pv[16];
#pragma unroll
        for (int i = 0; i < 16; i++) pv[i] = proj2[idx[i] * 16 + jj];

#pragma unroll
        for (int i = 0; i < 16; i++) {
            // sorted bag: (t < len) <=> bag[t] != PAD
            const bool upd = idx[i] < PADID;

            // ---- DPP butterfly all-gather: g[m] = pair (jj ^ GMAP[m]) ----
            v2f g[16];
            g[0] = (v2f){h0, h1};
            g[1] = (v2f){dppf<DPP_XOR1>(g[0].x), dppf<DPP_XOR1>(g[0].y)};
            g[2] = (v2f){dppf<DPP_XOR2>(g[0].x), dppf<DPP_XOR2>(g[0].y)};
            g[3] = (v2f){dppf<DPP_XOR2>(g[1].x), dppf<DPP_XOR2>(g[1].y)};
#pragma unroll
            for (int m = 0; m < 4; m++)
                g[4 + m] = (v2f){dppf<DPP_XOR7>(g[m].x), dppf<DPP_XOR7>(g[m].y)};
#pragma unroll
            for (int m = 0; m < 8; m++)
                g[8 + m] = (v2f){dppf<DPP_XORF>(g[m].x), dppf<DPP_XORF>(g[m].y)};

            // ---- 32 pk_fma: rows 2jj and 2jj+1 ----
            v2f a0 = (v2f){0.f, 0.f}, b0 = a0, a1 = a0, b1 = a0;
#pragma unroll
            for (int m = 0; m < 16; m += 2) {
                a0 = __builtin_elementwise_fma(w0[m],     g[m],     a0);
                b0 = __builtin_elementwise_fma(w0[m + 1], g[m + 1], b0);
                a1 = __builtin_elementwise_fma(w1[m],     g[m],     a1);
                b1 = __builtin_elementwise_fma(w1[m + 1], g[m + 1], b1);
            }
            float s0 = sb0 + pv[i].x + (a0.x + a0.y) + (b0.x + b0.y);
            float s1 = sb1 + pv[i].y + (a1.x + a1.y) + (b1.x + b1.y);

            // tanh(s) = 1 - 2/(e^{2s}+1); robust at both extremes, no clamp
            float e0 = __expf(2.f * s0);
            float e1 = __expf(2.f * s1);
            float th0 = 1.f - 2.f * __builtin_amdgcn_rcpf(e0 + 1.f);
            float th1 = 1.f - 2.f * __builtin_amdgcn_rcpf(e1 + 1.f);

            h0 = upd ? th0 : h0;
            h1 = upd ? th1 : h1;
        }
    }

    ((float2*)(out_h + (size_t)b * HID))[jj] = make_float2(h0, h1);
}

// ---------------- Fallback RNN (R4 exact) if ws can't hold proj ----------------
__global__ __launch_bounds__(128, 4) void rnn_kernel_noproj(
    const float* __restrict__ emb, const float* __restrict__ bagf,
    const float* __restrict__ W_ih, const float* __restrict__ W_hh,
    const float* __restrict__ b_ih, const float* __restrict__ b_hh,
    float* __restrict__ out_h)
{
    __shared__ float hbuf[4][32];
    const int tid = threadIdx.x;
    const int ib  = tid >> 5;
    const int j   = tid & 31;
    const int b   = blockIdx.x * 4 + ib;

    float wih[EMB];
#pragma unroll
    for (int k = 0; k < EMB; k++) wih[k] = W_ih[j * EMB + k];
    float whh[HID];
#pragma unroll
    for (int k = 0; k < HID; k++) whh[k] = W_hh[j * HID + k];
    const float sbias = b_ih[j] + b_hh[j];

    const float* bp = bagf + (size_t)b * 64;
    unsigned long long m0 = __ballot(bp[j]      < 4095.5f);
    unsigned long long m1 = __ballot(bp[32 + j] < 4095.5f);
    const int half = ib & 1;
    const int len = __popc((unsigned)(m0 >> (half * 32)))
                  + __popc((unsigned)(m1 >> (half * 32)));

    hbuf[ib][j] = 0.f;
    asm volatile("s_waitcnt lgkmcnt(0)" ::: "memory");

    float h = 0.f;
    const float* xb = emb + (size_t)b * (MAXLEN * EMB);
    for (int t = 0; t < MAXLEN; t++) {
        const float4* xp = (const float4*)(xb + t * EMB);
        float4 x0 = xp[0], x1 = xp[1], x2 = xp[2], x3 = xp[3], x4 = xp[4];
        float s = sbias;
        const float4* hb4 = (const float4*)hbuf[ib];
#pragma unroll
        for (int m = 0; m < 8; m++) {
            float4 hv = hb4[m];
            s += whh[4*m+0]*hv.x + whh[4*m+1]*hv.y
               + whh[4*m+2]*hv.z + whh[4*m+3]*hv.w;
        }
        s += wih[0]*x0.x + wih[1]*x0.y + wih[2]*x0.z + wih[3]*x0.w;
        s += wih[4]*x1.x + wih[5]*x1.y + wih[6]*x1.z + wih[7]*x1.w;
        s += wih[8]*x2.x + wih[9]*x2.y + wih[10]*x2.z + wih[11]*x2.w;
        s += wih[12]*x3.x + wih[13]*x3.y + wih[14]*x3.z + wih[15]*x3.w;
        s += wih[16]*x4.x + wih[17]*x4.y + wih[18]*x4.z + wih[19]*x4.w;
        s = fminf(fmaxf(s, -9.f), 9.f);
        float e = __expf(2.f * s);
        float th = (e - 1.f) * __builtin_amdgcn_rcpf(e + 1.f);
        h = (t < len) ? th : h;
        hbuf[ib][j] = h;
        asm volatile("s_waitcnt lgkmcnt(0)" ::: "memory");
    }
    out_h[(size_t)b * HID + j] = h;
}

extern "C" void kernel_launch(void* const* d_in, const int* in_sizes, int n_in,
                              void* d_out, int out_size, void* d_ws, size_t ws_size,
                              hipStream_t stream) {
    const int*   chars     = (const int*)d_in[0];
    const int*   colors    = (const int*)d_in[1];
    const float* emb_table = (const float*)d_in[2];
    const float* W_ih      = (const float*)d_in[3];
    const float* W_hh      = (const float*)d_in[4];
    const float* b_ih      = (const float*)d_in[5];
    const float* b_hh      = (const float*)d_in[6];

    const int B = in_sizes[0] / HW;      // 8192
    const int NBAG = (B + 3) / 4;        // 4 samples (waves) per block

    float* out     = (float*)d_out;
    float* out_h   = out;                                    // [B, 32]
    float* out_emb = out + (size_t)B * HID;                  // [B, 64, 20]
    float* out_bag = out_emb + (size_t)B * MAXLEN * EMB;     // [B, 64]

    const size_t proj_bytes = (size_t)(PADID + 1) * HID * sizeof(float);

    if (ws_size >= proj_bytes && (B % 8) == 0) {   // ws_size fixed -> same path every call
        float* proj = (float*)d_ws;
        bag_emb_wave_kernel<<<NBAG + PROJ_BLOCKS, 256, 0, stream>>>(
            chars, colors, emb_table, W_ih, out_emb, out_bag, proj, NBAG, B);
        rnn_kernel<<<B / 8, 128, 0, stream>>>(proj, out_bag, W_hh, b_ih, b_hh, out_h);
    } else {
        bag_emb_wave_kernel<<<NBAG, 256, 0, stream>>>(
            chars, colors, emb_table, W_ih, out_emb, out_bag, (float*)d_ws, NBAG, B);
        rnn_kernel_noproj<<<B / 4, 128, 0, stream>>>(out_emb, out_bag, W_ih, W_hh,
                                                     b_ih, b_hh, out_h);
    }
}

// Round 2
// 180.153 us; speedup vs baseline: 1.1343x; 1.1343x over previous
//
#include <hip/hip_runtime.h>

#define HW 1659      // 21*79
#define PADID 4096
#define EMB 20
#define HID 32
#define MAXLEN 64
#define PROJ_BLOCKS 128

typedef float v2f __attribute__((ext_vector_type(2)));

// DPP lane-permute helper (pure VALU, no LDS pipe). CTRL is an immediate.
template <int CTRL>
__device__ __forceinline__ float dppf(float v) {
    return __builtin_bit_cast(float,
        __builtin_amdgcn_update_dpp(0, __builtin_bit_cast(int, v),
                                    CTRL, 0xF, 0xF, true));
}
#define DPP_XOR1 0xB1   // quad_perm [1,0,3,2]
#define DPP_XOR2 0x4E   // quad_perm [2,3,0,1]
#define DPP_XOR7 0x141  // row_half_mirror (xor 7 within 16)
#define DPP_XORF 0x140  // row_mirror      (xor 15 within 16)

// ---------------- Kernel 1: 128-thread block-per-sample bag+emb ---------------
// R1 lesson: wave-per-sample + (256,8) VGPR cap serialized the global loads
// (VGPR=32, VALUBusy 6%). Back to block-per-sample with ALL loads hoisted
// (8 int4/thread = 32 VGPR payload, (128,4) bound so the compiler is never
// forced to re-materialize). 128-thread blocks: barriers span only 2 waves,
// 16 blocks/CU resident (vs 8) -> twice the independent groups pipelining.
// Readback is round-based: ids 0..2047 first, block-uniform early-exit when
// >=64 found (expected ~683 present there); round 1 only for adversarial data.
// Blocks >= nbag compute proj[g][j] = emb_table[g].W_ih[j] (fused tail,
// replaces the proj_kernel dispatch; only needs to finish before rnn_kernel).
__global__ __launch_bounds__(128, 4) void bag_emb_kernel(
    const int* __restrict__ chars, const int* __restrict__ colors,
    const float* __restrict__ emb_table, const float* __restrict__ W_ih,
    float* __restrict__ out_emb, float* __restrict__ out_bag,
    float* __restrict__ proj, int nbag)
{
    const int tid = threadIdx.x;

    if ((int)blockIdx.x >= nbag) {
        // ---- proj tail blocks ----
        const int gid = ((int)blockIdx.x - nbag) * 128 + tid;
        const int NP = (PADID + 1) * HID;          // 131104
        for (int idx = gid; idx < NP; idx += PROJ_BLOCKS * 128) {
            const int g = idx >> 5, j = idx & 31;
            const float* er = emb_table + (size_t)g * EMB;
            const float* wr = W_ih + j * EMB;
            float s = 0.f;
#pragma unroll
            for (int k = 0; k < EMB; k++) s += wr[k] * er[k];
            proj[idx] = s;
        }
        return;
    }

    __shared__ __align__(16) unsigned char pres[4096];
    __shared__ int bagl[64];
    __shared__ int wsum[2];

    const int lane = tid & 63;
    const int wv   = tid >> 6;
    const int b    = blockIdx.x;

    const int base = b * HW;
    const int pe = (4 - (base & 3)) & 3;          // peel to 16B alignment
    const int nv = (HW - pe) >> 2;                // always 414 int4 groups
    const int nt = HW - pe - (nv << 2);           // tail 0..3
    const int4* c4 = (const int4*)(chars + base + pe);
    const int4* k4 = (const int4*)(colors + base + pe);

    // ---- hoist ALL loads up front (8 int4 = 32 VGPRs, independent) ----
    int4 ca0 = c4[tid],       ka0 = k4[tid];
    int4 ca1 = c4[tid + 128], ka1 = k4[tid + 128];
    int4 ca2 = c4[tid + 256], ka2 = k4[tid + 256];     // 383 < 414 always
    const bool has3 = (tid + 384) < nv;                // tid < 30
    const int i3 = has3 ? tid + 384 : tid;
    int4 ca3 = c4[i3], ka3 = k4[i3];
    int gp = -1, gt = -1;
    if (tid < pe) gp = (chars[base + tid] << 4) + colors[base + tid];
    if (tid < nt) {
        const int i = base + pe + (nv << 2) + tid;
        gt = (chars[i] << 4) + colors[i];
    }

    // zero presence map: 256 uint4 over 128 threads
    ((uint4*)pres)[tid]       = make_uint4(0u, 0u, 0u, 0u);
    ((uint4*)pres)[tid + 128] = make_uint4(0u, 0u, 0u, 0u);
    if (tid < 64) bagl[tid] = PADID;
    __syncthreads();

    pres[(ca0.x << 4) + ka0.x] = 1;
    pres[(ca0.y << 4) + ka0.y] = 1;
    pres[(ca0.z << 4) + ka0.z] = 1;
    pres[(ca0.w << 4) + ka0.w] = 1;
    pres[(ca1.x << 4) + ka1.x] = 1;
    pres[(ca1.y << 4) + ka1.y] = 1;
    pres[(ca1.z << 4) + ka1.z] = 1;
    pres[(ca1.w << 4) + ka1.w] = 1;
    pres[(ca2.x << 4) + ka2.x] = 1;
    pres[(ca2.y << 4) + ka2.y] = 1;
    pres[(ca2.z << 4) + ka2.z] = 1;
    pres[(ca2.w << 4) + ka2.w] = 1;
    if (has3) {
        pres[(ca3.x << 4) + ka3.x] = 1;
        pres[(ca3.y << 4) + ka3.y] = 1;
        pres[(ca3.z << 4) + ka3.z] = 1;
        pres[(ca3.w << 4) + ka3.w] = 1;
    }
    if (gp >= 0) pres[gp] = 1;
    if (gt >= 0) pres[gt] = 1;
    __syncthreads();

    // ---- round-based readback: round r covers ids [2048r, 2048r+2048) ----
    // thread tid owns ids [2048r + 16*tid, +16): (r, tid, byte) order == id order
    const unsigned M = 0x01010101u;
    int base_cnt = 0;
#pragma unroll 1
    for (int r = 0; r < 2; r++) {
        const uint4 w = ((const uint4*)pres)[tid + (r << 7)];
        const int cnt = __popc(w.x & M) + __popc(w.y & M)
                      + __popc(w.z & M) + __popc(w.w & M);
        int pre = cnt;
#pragma unroll
        for (int d = 1; d < 64; d <<= 1) {
            const int v = __shfl_up(pre, d, 64);
            if (lane >= d) pre += v;
        }
        if (lane == 63) wsum[wv] = pre;
        __syncthreads();
        const int w0 = wsum[0], w1 = wsum[1];
        int p = base_cnt + (wv ? w0 : 0) + pre - cnt;     // exclusive prefix
        if (p < 64) {
            const unsigned wrd[4] = {w.x, w.y, w.z, w.w};
            const int idbase = (r << 11) + (tid << 4);
#pragma unroll
            for (int c = 0; c < 4; c++) {
#pragma unroll
                for (int k = 0; k < 4; k++) {
                    if ((wrd[c] >> (8 * k)) & 1) {
                        if (p < 64) bagl[p] = idbase + 4 * c + k;
                        p++;
                    }
                }
            }
        }
        base_cnt += w0 + w1;                 // block-uniform running total
        if (base_cnt >= 64) break;           // bag full -> skip round 1
        __syncthreads();                     // rare path: protect wsum reuse
    }
    __syncthreads();                         // bagl ready

    if (tid < 64) out_bag[(size_t)b * 64 + tid] = (float)bagl[tid];

    // gather embedding rows: 320 float4 over 128 threads, coalesced writes
    const float4* tab4 = (const float4*)emb_table;
    float4* dst4 = (float4*)(out_emb + (size_t)b * (MAXLEN * EMB));
#pragma unroll
    for (int m = 0; m < 3; m++) {
        const int q = tid + (m << 7);
        if (q < MAXLEN * 5) {
            const int t = q / 5;
            const int mm = q - t * 5;
            const int row = bagl[t];
            dst4[q] = tab4[row * 5 + mm];
        }
    }
}

// ------ Kernel 2: packed RNN, DPP all-gather, CHUNKED pv preload (16-deep) -----
__global__ __launch_bounds__(128)
__attribute__((amdgpu_waves_per_eu(2, 2)))
void rnn_kernel(
    const float* __restrict__ proj, const float* __restrict__ bagf,
    const float* __restrict__ W_hh,
    const float* __restrict__ b_ih, const float* __restrict__ b_hh,
    float* __restrict__ out_h)
{
    const int tid  = threadIdx.x;
    const int wv   = tid >> 6;
    const int lane = tid & 63;
    const int sl   = lane >> 4;        // sample slot within wave 0..3
    const int ib   = wv * 4 + sl;      // sample slot within block 0..7
    const int jj   = lane & 15;        // owns hidden units 2jj, 2jj+1
    const int b    = blockIdx.x * 8 + ib;

    // gather-position -> pair-xor map (butterfly: xor1, xor2, xor7, xor15)
    const int GMAP[16] = {0,1,2,3, 7,6,5,4, 15,14,13,12,11,10,9,8};

    // weights: w0[m]/w1[m] = rows (2jj, 2jj+1), column pair c = jj ^ GMAP[m]
    v2f w0[16], w1[16];
    const float2* wr0 = (const float2*)(W_hh + (2 * jj) * HID);
    const float2* wr1 = (const float2*)(W_hh + (2 * jj + 1) * HID);
#pragma unroll
    for (int m = 0; m < 16; m++) {
        const int c = jj ^ GMAP[m];
        float2 a = wr0[c], bb = wr1[c];
        w0[m] = (v2f){a.x, a.y};
        w1[m] = (v2f){bb.x, bb.y};
    }
    const float sb0 = b_ih[2 * jj]     + b_hh[2 * jj];
    const float sb1 = b_ih[2 * jj + 1] + b_hh[2 * jj + 1];

    const float* bps = bagf + (size_t)b * 64;
    const float2* proj2 = (const float2*)proj;   // row g -> proj2[g*16 + jj]

    float h0 = 0.f, h1 = 0.f;

#pragma unroll
    for (int ch = 0; ch < 4; ch++) {
        // ---- preload this chunk's 16 idx + pv (independent loads, MLP) ----
        int idx[16];
#pragma unroll
        for (int i = 0; i < 16; i++) idx[i] = (int)bps[ch * 16 + i];
        float2 pv[16];
#pragma unroll
        for (int i = 0; i < 16; i++) pv[i] = proj2[idx[i] * 16 + jj];

#pragma unroll
        for (int i = 0; i < 16; i++) {
            // sorted bag: (t < len) <=> bag[t] != PAD
            const bool upd = idx[i] < PADID;

            // ---- DPP butterfly all-gather: g[m] = pair (jj ^ GMAP[m]) ----
            v2f g[16];
            g[0] = (v2f){h0, h1};
            g[1] = (v2f){dppf<DPP_XOR1>(g[0].x), dppf<DPP_XOR1>(g[0].y)};
            g[2] = (v2f){dppf<DPP_XOR2>(g[0].x), dppf<DPP_XOR2>(g[0].y)};
            g[3] = (v2f){dppf<DPP_XOR2>(g[1].x), dppf<DPP_XOR2>(g[1].y)};
#pragma unroll
            for (int m = 0; m < 4; m++)
                g[4 + m] = (v2f){dppf<DPP_XOR7>(g[m].x), dppf<DPP_XOR7>(g[m].y)};
#pragma unroll
            for (int m = 0; m < 8; m++)
                g[8 + m] = (v2f){dppf<DPP_XORF>(g[m].x), dppf<DPP_XORF>(g[m].y)};

            // ---- 32 pk_fma: rows 2jj and 2jj+1 ----
            v2f a0 = (v2f){0.f, 0.f}, b0 = a0, a1 = a0, b1 = a0;
#pragma unroll
            for (int m = 0; m < 16; m += 2) {
                a0 = __builtin_elementwise_fma(w0[m],     g[m],     a0);
                b0 = __builtin_elementwise_fma(w0[m + 1], g[m + 1], b0);
                a1 = __builtin_elementwise_fma(w1[m],     g[m],     a1);
                b1 = __builtin_elementwise_fma(w1[m + 1], g[m + 1], b1);
            }
            float s0 = sb0 + pv[i].x + (a0.x + a0.y) + (b0.x + b0.y);
            float s1 = sb1 + pv[i].y + (a1.x + a1.y) + (b1.x + b1.y);

            // tanh(s) = 1 - 2/(e^{2s}+1); robust at both extremes, no clamp
            float e0 = __expf(2.f * s0);
            float e1 = __expf(2.f * s1);
            float th0 = 1.f - 2.f * __builtin_amdgcn_rcpf(e0 + 1.f);
            float th1 = 1.f - 2.f * __builtin_amdgcn_rcpf(e1 + 1.f);

            h0 = upd ? th0 : h0;
            h1 = upd ? th1 : h1;
        }
    }

    ((float2*)(out_h + (size_t)b * HID))[jj] = make_float2(h0, h1);
}

// ---------------- Fallback RNN (R4 exact) if ws can't hold proj ----------------
__global__ __launch_bounds__(128, 4) void rnn_kernel_noproj(
    const float* __restrict__ emb, const float* __restrict__ bagf,
    const float* __restrict__ W_ih, const float* __restrict__ W_hh,
    const float* __restrict__ b_ih, const float* __restrict__ b_hh,
    float* __restrict__ out_h)
{
    __shared__ float hbuf[4][32];
    const int tid = threadIdx.x;
    const int ib  = tid >> 5;
    const int j   = tid & 31;
    const int b   = blockIdx.x * 4 + ib;

    float wih[EMB];
#pragma unroll
    for (int k = 0; k < EMB; k++) wih[k] = W_ih[j * EMB + k];
    float whh[HID];
#pragma unroll
    for (int k = 0; k < HID; k++) whh[k] = W_hh[j * HID + k];
    const float sbias = b_ih[j] + b_hh[j];

    const float* bp = bagf + (size_t)b * 64;
    unsigned long long m0 = __ballot(bp[j]      < 4095.5f);
    unsigned long long m1 = __ballot(bp[32 + j] < 4095.5f);
    const int half = ib & 1;
    const int len = __popc((unsigned)(m0 >> (half * 32)))
                  + __popc((unsigned)(m1 >> (half * 32)));

    hbuf[ib][j] = 0.f;
    asm volatile("s_waitcnt lgkmcnt(0)" ::: "memory");

    float h = 0.f;
    const float* xb = emb + (size_t)b * (MAXLEN * EMB);
    for (int t = 0; t < MAXLEN; t++) {
        const float4* xp = (const float4*)(xb + t * EMB);
        float4 x0 = xp[0], x1 = xp[1], x2 = xp[2], x3 = xp[3], x4 = xp[4];
        float s = sbias;
        const float4* hb4 = (const float4*)hbuf[ib];
#pragma unroll
        for (int m = 0; m < 8; m++) {
            float4 hv = hb4[m];
            s += whh[4*m+0]*hv.x + whh[4*m+1]*hv.y
               + whh[4*m+2]*hv.z + whh[4*m+3]*hv.w;
        }
        s += wih[0]*x0.x + wih[1]*x0.y + wih[2]*x0.z + wih[3]*x0.w;
        s += wih[4]*x1.x + wih[5]*x1.y + wih[6]*x1.z + wih[7]*x1.w;
        s += wih[8]*x2.x + wih[9]*x2.y + wih[10]*x2.z + wih[11]*x2.w;
        s += wih[12]*x3.x + wih[13]*x3.y + wih[14]*x3.z + wih[15]*x3.w;
        s += wih[16]*x4.x + wih[17]*x4.y + wih[18]*x4.z + wih[19]*x4.w;
        s = fminf(fmaxf(s, -9.f), 9.f);
        float e = __expf(2.f * s);
        float th = (e - 1.f) * __builtin_amdgcn_rcpf(e + 1.f);
        h = (t < len) ? th : h;
        hbuf[ib][j] = h;
        asm volatile("s_waitcnt lgkmcnt(0)" ::: "memory");
    }
    out_h[(size_t)b * HID + j] = h;
}

extern "C" void kernel_launch(void* const* d_in, const int* in_sizes, int n_in,
                              void* d_out, int out_size, void* d_ws, size_t ws_size,
                              hipStream_t stream) {
    const int*   chars     = (const int*)d_in[0];
    const int*   colors    = (const int*)d_in[1];
    const float* emb_table = (const float*)d_in[2];
    const float* W_ih      = (const float*)d_in[3];
    const float* W_hh      = (const float*)d_in[4];
    const float* b_ih      = (const float*)d_in[5];
    const float* b_hh      = (const float*)d_in[6];

    const int B = in_sizes[0] / HW;      // 8192

    float* out     = (float*)d_out;
    float* out_h   = out;                                    // [B, 32]
    float* out_emb = out + (size_t)B * HID;                  // [B, 64, 20]
    float* out_bag = out_emb + (size_t)B * MAXLEN * EMB;     // [B, 64]

    const size_t proj_bytes = (size_t)(PADID + 1) * HID * sizeof(float);

    if (ws_size >= proj_bytes && (B % 8) == 0) {   // ws_size fixed -> same path every call
        float* proj = (float*)d_ws;
        bag_emb_kernel<<<B + PROJ_BLOCKS, 128, 0, stream>>>(
            chars, colors, emb_table, W_ih, out_emb, out_bag, proj, B);
        rnn_kernel<<<B / 8, 128, 0, stream>>>(proj, out_bag, W_hh, b_ih, b_hh, out_h);
    } else {
        bag_emb_kernel<<<B, 128, 0, stream>>>(
            chars, colors, emb_table, W_ih, out_emb, out_bag, (float*)d_ws, B);
        rnn_kernel_noproj<<<B / 4, 128, 0, stream>>>(out_emb, out_bag, W_ih, W_hh,
                                                     b_ih, b_hh, out_h);
    }
}